// Round 1
// 4287.010 us; speedup vs baseline: 1.1458x; 1.1458x over previous
//
#include <hip/hip_runtime.h>

#define H    1024
#define OUTD 768
#define BSZ  512
#define TSTEPS 256
#define N3H  3072
#define NEXT 4864   // 4*H (interleaved gates) + OUTD (fc output columns)
#define TILE_E 4096     // elements per 64x64 bf16 tile
#define MT_E   65536    // elements per tile-row (16 k-tiles)
#define SLOT_E 524288   // BSZ*H

typedef __attribute__((ext_vector_type(8))) short bf16x8;
typedef __attribute__((ext_vector_type(4))) float f32x4;

__device__ __forceinline__ unsigned short f2bf(float f){
  unsigned u = __builtin_bit_cast(unsigned, f);
  u += 0x7fffu + ((u >> 16) & 1u);           // round-to-nearest-even
  return (unsigned short)(u >> 16);
}
__device__ __forceinline__ float sigm(float x){ return 1.f/(1.f+__expf(-x)); }

// XOR-swizzled offset inside a 64x64 bf16 tile: row r, col c.
// Granule (16B = 8 elems) index is XORed with (r&7) -> conflict-free ds_read_b128.
__device__ __forceinline__ int swz_off(int r, int c){
  return (r<<6) | (((c>>3) ^ (r&7))<<3) | (c&7);
}

// async global->LDS, 16B per lane; LDS dest is wave-uniform base + lane*16
#define GLOAD16(gp, lp) __builtin_amdgcn_global_load_lds( \
    (__attribute__((address_space(1))) void*)(gp), \
    (__attribute__((address_space(3))) void*)(lp), 16, 0, 0)

// ---------------- conversion / assembly kernels ----------------
__global__ void conv_bf(unsigned short* dst, const float* src, int n){
  int i = blockIdx.x*256 + threadIdx.x;
  if (i < n) dst[i] = f2bf(src[i]);
}
__global__ void conv_rows(unsigned short* dst, const float* src, int rows, int cols,
                          int sstride, int soff){
  int i = blockIdx.x*256 + threadIdx.x;
  if (i < rows*cols){ int r = i/cols, c = i - r*cols; dst[i] = f2bf(src[r*sstride + soff + c]); }
}
__global__ void transp_fcw(unsigned short* dst, const float* fcw){
  __shared__ float tile[64][65];
  int k0 = blockIdx.x*64, o0 = blockIdx.y*64;
  int t = threadIdx.x; int rr = t>>2, cs = (t&3)*16;
  for (int j=0;j<16;j++) tile[rr][cs+j] = fcw[(size_t)(o0+rr)*2048 + k0+cs+j];
  __syncthreads();
  for (int j=0;j<16;j++) dst[(size_t)(k0+rr)*768 + o0+cs+j] = f2bf(tile[cs+j][rr]);
}

// W_ext in tile-blocked swizzled layout: tile (n>>6, k>>6), internal XOR swizzle.
__global__ void asm_wext(unsigned short* Wext, const float* Wcomb, const float* Whh,
                         const float* fcW){
  int idx = blockIdx.x*256 + threadIdx.x;
  if (idx >= NEXT*H) return;
  int n = idx >> 10, k = idx & 1023;
  float v;
  if (n < 4096){
    int c = (n>>4)&3, jj = ((n>>6)<<4) | (n&15);
    if (c==0)      v = Wcomb[(size_t)jj*H + k]       + Whh[(size_t)jj*H + k];
    else if (c==1) v = Wcomb[(size_t)(H+jj)*H + k]   + Whh[(size_t)(H+jj)*H + k];
    else if (c==2) v = Wcomb[(size_t)(2*H+jj)*H + k];
    else           v = Whh[(size_t)(2*H+jj)*H + k];
  } else {
    v = fcW[(size_t)(n-4096)*2048 + k];
  }
  Wext[(size_t)(n>>6)*MT_E + (k>>6)*TILE_E + swz_off(n&63, k&63)] = f2bf(v);
}

// const_ext [BSZ][NEXT] fp32 (plain layout, read in epilogue)
__global__ void asm_const(float* cst, const float* dmat, const float* fcctx,
                          const float* b_hh){
  int idx = blockIdx.x*256 + threadIdx.x;
  if (idx >= BSZ*NEXT) return;
  int b = idx / NEXT, n = idx - b*NEXT;
  float v;
  if (n < 4096){
    int c = (n>>4)&3, jj = ((n>>6)<<4) | (n&15);
    if (c==0)      v = dmat[(size_t)b*N3H + jj]       + b_hh[jj];
    else if (c==1) v = dmat[(size_t)b*N3H + H + jj]   + b_hh[H+jj];
    else if (c==2) v = dmat[(size_t)b*N3H + 2*H + jj];
    else           v = b_hh[2*H + jj];
  } else {
    v = fcctx[(size_t)b*OUTD + (n-4096)];
  }
  cst[idx] = v;
}

// step-0 GRU cell; writes h bf16 into tile-blocked swizzled layout
__global__ void gru0(const float* gi, const float* gh, const float* hidden,
                     unsigned short* hbf, float* hf){
  int idx = blockIdx.x*256 + threadIdx.x;
  if (idx >= BSZ*H) return;
  int b = idx >> 10, j = idx & 1023;
  float r  = sigm(gi[(size_t)b*N3H + j]       + gh[(size_t)b*N3H + j]);
  float z  = sigm(gi[(size_t)b*N3H + H + j]   + gh[(size_t)b*N3H + H + j]);
  float nn = tanhf(gi[(size_t)b*N3H + 2*H + j] + r*gh[(size_t)b*N3H + 2*H + j]);
  float ho = hidden[idx];
  float hn = nn + z*(ho - nn);
  hf[idx] = hn;
  hbf[(size_t)(b>>6)*MT_E + (j>>6)*TILE_E + swz_off(b&63, j&63)] = f2bf(hn);
}

// ---------------- prologue GEMM (plain layouts, unchanged) ----------------
__global__ __launch_bounds__(256) void gemm_bt(const unsigned short* __restrict__ A,
    const unsigned short* __restrict__ Bt, const float* __restrict__ bias,
    float* __restrict__ C, int N, int K){
  __shared__ unsigned short As[64][72];
  __shared__ unsigned short Bs[64][72];
  int tid = threadIdx.x, wave = tid>>6, lane = tid&63;
  int m0 = blockIdx.y*64, n0 = blockIdx.x*64;
  int lr = tid>>2, lc = (tid&3)*16;
  const unsigned short* Ag = A + (size_t)(m0+lr)*K + lc;
  const unsigned short* Bg = Bt + (size_t)(n0+lr)*K + lc;
  f32x4 acc[4];
  #pragma unroll
  for (int c=0;c<4;c++) acc[c] = (f32x4)0.f;
  int arow = wave*16 + (lane&15);
  int koff = (lane>>4)*8;
  for (int k0=0;k0<K;k0+=64){
    *(uint4*)&As[lr][lc]   = *(const uint4*)(Ag + k0);
    *(uint4*)&As[lr][lc+8] = *(const uint4*)(Ag + k0 + 8);
    *(uint4*)&Bs[lr][lc]   = *(const uint4*)(Bg + k0);
    *(uint4*)&Bs[lr][lc+8] = *(const uint4*)(Bg + k0 + 8);
    __syncthreads();
    #pragma unroll
    for (int kk=0;kk<2;kk++){
      bf16x8 af = *(const bf16x8*)&As[arow][kk*32 + koff];
      #pragma unroll
      for (int c=0;c<4;c++){
        bf16x8 bfr = *(const bf16x8*)&Bs[c*16 + (lane&15)][kk*32 + koff];
        acc[c] = __builtin_amdgcn_mfma_f32_16x16x32_bf16(af, bfr, acc[c], 0, 0, 0);
      }
    }
    __syncthreads();
  }
  int col = lane&15, rbase = m0 + wave*16 + (lane>>4)*4;
  #pragma unroll
  for (int c=0;c<4;c++){
    int n = n0 + c*16 + col;
    float bv = bias ? bias[n] : 0.f;
    #pragma unroll
    for (int i=0;i<4;i++) C[(size_t)(rbase+i)*N + n] = acc[c][i] + bv;
  }
}

// ---------------- improved 64x64 GEMM core ----------------
// A,B in tile-blocked swizzled layout (16 k-tiles of 4096 elems per tile-row).
// Double-buffered, async global_load_lds staging, one barrier per K-step.
__device__ __forceinline__ void mm64(const unsigned short* __restrict__ At,
                                     const unsigned short* __restrict__ Bt,
                                     unsigned short* sA, unsigned short* sB,
                                     f32x4 acc[4]){
  const int tid = threadIdx.x, wave = tid>>6, lane = tid&63;
  const int l8 = lane>>4, lx = lane&7;
  const int xg = ((l8 ^ lx) << 3);
  const int offA = ((wave<<4) | (lane&15))*64 + xg;   // arow*64 + swz granule
  const int offB = (lane&15)*64 + xg;
  const unsigned short* ga = At + (wave<<9) + (lane<<3);
  const unsigned short* gb = Bt + (wave<<9) + (lane<<3);
  unsigned short* lA = sA + (wave<<9);   // wave-uniform LDS base
  unsigned short* lB = sB + (wave<<9);
  // stage k-tile 0 -> buf 0
  GLOAD16(ga, lA); GLOAD16(ga+2048, lA+2048);
  GLOAD16(gb, lB); GLOAD16(gb+2048, lB+2048);
  __syncthreads();
  #pragma unroll 2
  for (int kt=0; kt<16; kt++){
    const int cb = kt & 1;
    if (kt < 15){   // prefetch next k-tile into other buffer (in flight during MFMA)
      const unsigned short* gan = ga + (kt+1)*TILE_E;
      const unsigned short* gbn = gb + (kt+1)*TILE_E;
      const int bo = (cb^1) << 12;
      GLOAD16(gan, lA+bo); GLOAD16(gan+2048, lA+bo+2048);
      GLOAD16(gbn, lB+bo); GLOAD16(gbn+2048, lB+bo+2048);
    }
    const unsigned short* A0 = sA + (cb<<12);
    const unsigned short* B0 = sB + (cb<<12);
    #pragma unroll
    for (int kk=0; kk<2; kk++){
      bf16x8 av = *(const bf16x8*)(A0 + (offA ^ (kk<<5)));
      #pragma unroll
      for (int c=0; c<4; c++){
        bf16x8 bv = *(const bf16x8*)(B0 + ((offB + (c<<10)) ^ (kk<<5)));
        acc[c] = __builtin_amdgcn_mfma_f32_16x16x32_bf16(av, bv, acc[c], 0, 0, 0);
      }
    }
    __syncthreads();   // drains vmcnt(0): prefetched buffer ready; readers done with cb
  }
}

// ---------------- fused recurrence step ----------------
// grid (64,8) deferred (gates only) or (76,8) fused (gates + out tiles)
__global__ __launch_bounds__(256) void gemm_rec(const unsigned short* __restrict__ hin,
    const float* __restrict__ hfin, const unsigned short* __restrict__ Wext,
    const float* __restrict__ cst, float* __restrict__ outp,
    unsigned short* __restrict__ hout, float* __restrict__ hfout){
  __shared__ __align__(16) unsigned short sA[2*4096];
  __shared__ __align__(16) unsigned short sB[2*4096];
  // XCD swizzle: cluster the 8 m-blocks sharing a B panel onto one XCD
  const int gx = gridDim.x;
  const int f = blockIdx.x + gx*blockIdx.y;
  const int q = f & 7, mm = f >> 3;
  const int v = q*gx + mm;               // bijection for gridDim.y == 8
  const int bx = v >> 3, by = v & 7;
  f32x4 acc[4];
  #pragma unroll
  for (int c=0;c<4;c++) acc[c] = (f32x4)0.f;
  mm64(hin + (size_t)by*MT_E, Wext + (size_t)bx*MT_E, sA, sB, acc);
  const int tid = threadIdx.x, wave = tid>>6, lane = tid&63;
  const int col = lane & 15;
  const int rbase = by*64 + wave*16 + (lane>>4)*4;
  if (bx < 64){
    // gate tile: 16-col sub-blocks are r, z, i_n, h_n for h-dims jj = bx*16 + col
    const int jj = bx*16 + col;
    const float* cbp = cst + bx*64 + col;
    const int tb = (jj>>6)*TILE_E;
    #pragma unroll
    for (int i=0;i<4;i++){
      const int b = rbase + i;
      const float* cr = cbp + (size_t)b*NEXT;
      float r  = sigm(acc[0][i] + cr[0]);
      float z  = sigm(acc[1][i] + cr[16]);
      float nn = tanhf((acc[2][i] + cr[32]) + r*(acc[3][i] + cr[48]));
      float hn = nn + z*(hfin[(size_t)b*H + jj] - nn);
      hfout[(size_t)b*H + jj] = hn;
      hout[(size_t)(b>>6)*MT_E + tb + swz_off(b&63, jj&63)] = f2bf(hn);
    }
  } else {
    // output tile (fused mode only)
    const int o0 = (bx-64)*64;
    #pragma unroll
    for (int c=0;c<4;c++){
      const int oc = o0 + c*16 + col;
      #pragma unroll
      for (int i=0;i<4;i++){
        const int b = rbase + i;
        outp[(size_t)b*OUTD + oc] = acc[c][i] + cst[(size_t)b*NEXT + 4096 + oc];
      }
    }
  }
}

// ---------------- deferred output GEMM: out[s] = hist[s] @ fcW_h^T + fcctx ----------------
// grid (12, 2048): bx = out n-tile, by = global m-tile (s*8 + mb)
__global__ __launch_bounds__(256) void gemm_out(const unsigned short* __restrict__ hist,
    const unsigned short* __restrict__ Wext, const float* __restrict__ fcctx,
    float* __restrict__ outp){
  __shared__ __align__(16) unsigned short sA[2*4096];
  __shared__ __align__(16) unsigned short sB[2*4096];
  const int bx = blockIdx.x;
  const int g  = blockIdx.y;
  f32x4 acc[4];
  #pragma unroll
  for (int c=0;c<4;c++) acc[c] = (f32x4)0.f;
  mm64(hist + (size_t)g*MT_E, Wext + (size_t)(64+bx)*MT_E, sA, sB, acc);
  const int tid = threadIdx.x, wave = tid>>6, lane = tid&63;
  const int col = lane & 15;
  const int s = g>>3, mb = g&7;
  const int rb = mb*64 + wave*16 + (lane>>4)*4;
  float* outs = outp + (size_t)s*BSZ*OUTD;
  #pragma unroll
  for (int c=0;c<4;c++){
    const int oc = bx*64 + c*16 + col;
    #pragma unroll
    for (int i=0;i<4;i++){
      const int b = rb + i;
      outs[(size_t)b*OUTD + oc] = acc[c][i] + fcctx[(size_t)b*OUTD + oc];
    }
  }
}

// ---------------- host ----------------
extern "C" void kernel_launch(void* const* d_in, const int* in_sizes, int n_in,
                              void* d_out, int out_size, void* d_ws, size_t ws_size,
                              hipStream_t stream){
  const float* src    = (const float*)d_in[0];   // [1,512,768]
  const float* hidden = (const float*)d_in[1];   // [1,512,1024]
  const float* W_ih   = (const float*)d_in[2];   // [3072,768]
  const float* W_hh   = (const float*)d_in[3];   // [3072,1024]
  const float* b_ih   = (const float*)d_in[4];   // [3072]
  const float* b_hh   = (const float*)d_in[5];   // [3072]
  const float* fc_W   = (const float*)d_in[6];   // [768,2048]
  const float* fc_b   = (const float*)d_in[7];   // [768]
  float* outp = (float*)d_out;                   // [256,512,768]

  char* p = (char*)d_ws;
  auto alloc = [&](size_t bytes){ char* r = p; p += (bytes + 255) & ~(size_t)255; return r; };
  unsigned short* Wih_bf   = (unsigned short*)alloc((size_t)N3H*OUTD*2);
  unsigned short* Whh_bf   = (unsigned short*)alloc((size_t)N3H*H*2);
  unsigned short* fcWbt    = (unsigned short*)alloc((size_t)OUTD*H*2);
  unsigned short* fcWT     = (unsigned short*)alloc((size_t)H*OUTD*2);
  unsigned short* ctx_bf   = (unsigned short*)alloc((size_t)BSZ*H*2);
  unsigned short* x0_bf    = (unsigned short*)alloc((size_t)BSZ*OUTD*2);
  float*          fcctx    = (float*)alloc((size_t)BSZ*OUTD*4);
  unsigned short* fcctx_bf = (unsigned short*)alloc((size_t)BSZ*OUTD*2);
  float*          Wcomb    = (float*)alloc((size_t)N3H*H*4);
  float*          dmat     = (float*)alloc((size_t)BSZ*N3H*4);
  unsigned short* Wext     = (unsigned short*)alloc((size_t)NEXT*H*2);
  float*          cst      = (float*)alloc((size_t)BSZ*NEXT*4);
  float*          gi       = (float*)alloc((size_t)BSZ*N3H*4);
  float*          gh       = (float*)alloc((size_t)BSZ*N3H*4);
  unsigned short* hbf      = (unsigned short*)alloc((size_t)2*BSZ*H*2);
  float*          hf       = (float*)alloc((size_t)2*BSZ*H*4);

  size_t used = (size_t)(p - (char*)d_ws);
  size_t hist_bytes = (size_t)TSTEPS*BSZ*H*2;   // 268 MB bf16 h-history
  bool defer = (used + hist_bytes + 4096) <= ws_size;
  unsigned short* hist = defer ? (unsigned short*)alloc(hist_bytes) : nullptr;

  auto cdiv = [](int a, int b){ return (a + b - 1)/b; };

  // --- prologue: conversions ---
  conv_bf<<<cdiv(N3H*OUTD,256),256,0,stream>>>(Wih_bf, W_ih, N3H*OUTD);
  conv_bf<<<cdiv(N3H*H,256),256,0,stream>>>(Whh_bf, W_hh, N3H*H);
  conv_bf<<<cdiv(BSZ*H,256),256,0,stream>>>(ctx_bf, hidden, BSZ*H);
  conv_bf<<<cdiv(BSZ*OUTD,256),256,0,stream>>>(x0_bf, src, BSZ*OUTD);
  conv_rows<<<cdiv(OUTD*H,256),256,0,stream>>>(fcWbt, fc_W, OUTD, H, 2*H, H);
  transp_fcw<<<dim3(16,12),256,0,stream>>>(fcWT, fc_W);

  // --- prologue: weight-folding GEMMs ---
  gemm_bt<<<dim3(H/64, N3H/64),256,0,stream>>>(Wih_bf, fcWT, nullptr, Wcomb, H, OUTD);
  gemm_bt<<<dim3(OUTD/64, BSZ/64),256,0,stream>>>(ctx_bf, fcWbt, fc_b, fcctx, OUTD, H);
  conv_bf<<<cdiv(BSZ*OUTD,256),256,0,stream>>>(fcctx_bf, fcctx, BSZ*OUTD);
  gemm_bt<<<dim3(N3H/64, BSZ/64),256,0,stream>>>(fcctx_bf, Wih_bf, b_ih, dmat, N3H, OUTD);

  asm_wext<<<cdiv(NEXT*H,256),256,0,stream>>>(Wext, Wcomb, W_hh, fc_W);
  asm_const<<<cdiv(BSZ*NEXT,256),256,0,stream>>>(cst, dmat, fcctx, b_hh);

  // --- step 0 (direct form, x0 = src[0]) ---
  gemm_bt<<<dim3(N3H/64, BSZ/64),256,0,stream>>>(x0_bf, Wih_bf, b_ih, gi, N3H, OUTD);
  gemm_bt<<<dim3(N3H/64, BSZ/64),256,0,stream>>>(ctx_bf, Whh_bf, b_hh, gh, N3H, H);

  if (defer){
    // h_1 -> hist slot 0
    gru0<<<cdiv(BSZ*H,256),256,0,stream>>>(gi, gh, hidden, hist, hf + SLOT_E);
    // gates-only sequential chain: 512 blocks = exactly 2/CU
    for (int t=1; t<TSTEPS; t++){
      gemm_rec<<<dim3(64,8),256,0,stream>>>(
          hist + (size_t)(t-1)*SLOT_E, hf + (size_t)(t&1)*SLOT_E,
          Wext, cst, nullptr,
          hist + (size_t)t*SLOT_E, hf + (size_t)((t+1)&1)*SLOT_E);
    }
    // all outputs in one big parallel GEMM
    gemm_out<<<dim3(12,2048),256,0,stream>>>(hist, Wext, fcctx, outp);
  } else {
    gru0<<<cdiv(BSZ*H,256),256,0,stream>>>(gi, gh, hidden, hbf + SLOT_E, hf + SLOT_E);
    for (int t=1; t<=TSTEPS; t++){
      gemm_rec<<<dim3(76,8),256,0,stream>>>(
          hbf + (size_t)(t&1)*SLOT_E, hf + (size_t)(t&1)*SLOT_E,
          Wext, cst, outp + (size_t)(t-1)*BSZ*OUTD,
          hbf + (size_t)((t+1)&1)*SLOT_E, hf + (size_t)((t+1)&1)*SLOT_E);
    }
  }
}

// Round 2
// 3838.509 us; speedup vs baseline: 1.2797x; 1.1168x over previous
//
#include <hip/hip_runtime.h>

#define H    1024
#define OUTD 768
#define BSZ  512
#define TSTEPS 256
#define N3H  3072
#define NEXT 4864   // 4*H (interleaved gates) + OUTD (fc output columns)
#define TILE_E 4096     // elements per 64x64 bf16 tile
#define MT_E   65536    // elements per 64-wide tile-row (16 k-tiles)
#define SLOT_E 524288   // BSZ*H

typedef __attribute__((ext_vector_type(8))) short bf16x8;
typedef __attribute__((ext_vector_type(4))) float f32x4;

__device__ __forceinline__ unsigned short f2bf(float f){
  unsigned u = __builtin_bit_cast(unsigned, f);
  u += 0x7fffu + ((u >> 16) & 1u);           // round-to-nearest-even
  return (unsigned short)(u >> 16);
}
__device__ __forceinline__ float sigm(float x){ return 1.f/(1.f+__expf(-x)); }

// XOR-swizzled offset inside a 64x64 bf16 tile: row r, col c.
__device__ __forceinline__ int swz_off(int r, int c){
  return (r<<6) | (((c>>3) ^ (r&7))<<3) | (c&7);
}

// async global->LDS, 16B per lane; LDS dest is wave-uniform base + lane*16
#define GLOAD16(gp, lp) __builtin_amdgcn_global_load_lds( \
    (__attribute__((address_space(1))) void*)(gp), \
    (__attribute__((address_space(3))) void*)(lp), 16, 0, 0)

template<int N> __device__ __forceinline__ void waitv(){
  if constexpr (N==0)      asm volatile("s_waitcnt vmcnt(0)" ::: "memory");
  else if constexpr (N==4) asm volatile("s_waitcnt vmcnt(4)" ::: "memory");
  else if constexpr (N==6) asm volatile("s_waitcnt vmcnt(6)" ::: "memory");
  else if constexpr (N==8) asm volatile("s_waitcnt vmcnt(8)" ::: "memory");
}
__device__ __forceinline__ void waitlgkm0(){
  asm volatile("s_waitcnt lgkmcnt(0)" ::: "memory");
}
__device__ __forceinline__ void bar(){ __builtin_amdgcn_s_barrier(); }

// ---------------- conversion / assembly kernels ----------------
__global__ void conv_bf(unsigned short* dst, const float* src, int n){
  int i = blockIdx.x*256 + threadIdx.x;
  if (i < n) dst[i] = f2bf(src[i]);
}
__global__ void conv_rows(unsigned short* dst, const float* src, int rows, int cols,
                          int sstride, int soff){
  int i = blockIdx.x*256 + threadIdx.x;
  if (i < rows*cols){ int r = i/cols, c = i - r*cols; dst[i] = f2bf(src[r*sstride + soff + c]); }
}
__global__ void transp_fcw(unsigned short* dst, const float* fcw){
  __shared__ float tile[64][65];
  int k0 = blockIdx.x*64, o0 = blockIdx.y*64;
  int t = threadIdx.x; int rr = t>>2, cs = (t&3)*16;
  for (int j=0;j<16;j++) tile[rr][cs+j] = fcw[(size_t)(o0+rr)*2048 + k0+cs+j];
  __syncthreads();
  for (int j=0;j<16;j++) dst[(size_t)(k0+rr)*768 + o0+cs+j] = f2bf(tile[cs+j][rr]);
}

// W_ext in tile-blocked swizzled layout: tile (n>>6, k>>6), internal XOR swizzle.
__global__ void asm_wext(unsigned short* Wext, const float* Wcomb, const float* Whh,
                         const float* fcW){
  int idx = blockIdx.x*256 + threadIdx.x;
  if (idx >= NEXT*H) return;
  int n = idx >> 10, k = idx & 1023;
  float v;
  if (n < 4096){
    int c = (n>>4)&3, jj = ((n>>6)<<4) | (n&15);
    if (c==0)      v = Wcomb[(size_t)jj*H + k]       + Whh[(size_t)jj*H + k];
    else if (c==1) v = Wcomb[(size_t)(H+jj)*H + k]   + Whh[(size_t)(H+jj)*H + k];
    else if (c==2) v = Wcomb[(size_t)(2*H+jj)*H + k];
    else           v = Whh[(size_t)(2*H+jj)*H + k];
  } else {
    v = fcW[(size_t)(n-4096)*2048 + k];
  }
  Wext[(size_t)(n>>6)*MT_E + (k>>6)*TILE_E + swz_off(n&63, k&63)] = f2bf(v);
}

// const_ext [BSZ][NEXT] fp32
__global__ void asm_const(float* cst, const float* dmat, const float* fcctx,
                          const float* b_hh){
  int idx = blockIdx.x*256 + threadIdx.x;
  if (idx >= BSZ*NEXT) return;
  int b = idx / NEXT, n = idx - b*NEXT;
  float v;
  if (n < 4096){
    int c = (n>>4)&3, jj = ((n>>6)<<4) | (n&15);
    if (c==0)      v = dmat[(size_t)b*N3H + jj]       + b_hh[jj];
    else if (c==1) v = dmat[(size_t)b*N3H + H + jj]   + b_hh[H+jj];
    else if (c==2) v = dmat[(size_t)b*N3H + 2*H + jj];
    else           v = b_hh[2*H + jj];
  } else {
    v = fcctx[(size_t)b*OUTD + (n-4096)];
  }
  cst[idx] = v;
}

// step-0 GRU cell; writes h bf16 into tile-blocked swizzled layout
__global__ void gru0(const float* gi, const float* gh, const float* hidden,
                     unsigned short* hbf, float* hf){
  int idx = blockIdx.x*256 + threadIdx.x;
  if (idx >= BSZ*H) return;
  int b = idx >> 10, j = idx & 1023;
  float r  = sigm(gi[(size_t)b*N3H + j]       + gh[(size_t)b*N3H + j]);
  float z  = sigm(gi[(size_t)b*N3H + H + j]   + gh[(size_t)b*N3H + H + j]);
  float nn = tanhf(gi[(size_t)b*N3H + 2*H + j] + r*gh[(size_t)b*N3H + 2*H + j]);
  float ho = hidden[idx];
  float hn = nn + z*(ho - nn);
  hf[idx] = hn;
  hbf[(size_t)(b>>6)*MT_E + (j>>6)*TILE_E + swz_off(b&63, j&63)] = f2bf(hn);
}

// ---------------- prologue GEMM (plain layouts) ----------------
__global__ __launch_bounds__(256) void gemm_bt(const unsigned short* __restrict__ A,
    const unsigned short* __restrict__ Bt, const float* __restrict__ bias,
    float* __restrict__ C, int N, int K){
  __shared__ unsigned short As[64][72];
  __shared__ unsigned short Bs[64][72];
  int tid = threadIdx.x, wave = tid>>6, lane = tid&63;
  int m0 = blockIdx.y*64, n0 = blockIdx.x*64;
  int lr = tid>>2, lc = (tid&3)*16;
  const unsigned short* Ag = A + (size_t)(m0+lr)*K + lc;
  const unsigned short* Bg = Bt + (size_t)(n0+lr)*K + lc;
  f32x4 acc[4];
  #pragma unroll
  for (int c=0;c<4;c++) acc[c] = (f32x4)0.f;
  int arow = wave*16 + (lane&15);
  int koff = (lane>>4)*8;
  for (int k0=0;k0<K;k0+=64){
    *(uint4*)&As[lr][lc]   = *(const uint4*)(Ag + k0);
    *(uint4*)&As[lr][lc+8] = *(const uint4*)(Ag + k0 + 8);
    *(uint4*)&Bs[lr][lc]   = *(const uint4*)(Bg + k0);
    *(uint4*)&Bs[lr][lc+8] = *(const uint4*)(Bg + k0 + 8);
    __syncthreads();
    #pragma unroll
    for (int kk=0;kk<2;kk++){
      bf16x8 af = *(const bf16x8*)&As[arow][kk*32 + koff];
      #pragma unroll
      for (int c=0;c<4;c++){
        bf16x8 bfr = *(const bf16x8*)&Bs[c*16 + (lane&15)][kk*32 + koff];
        acc[c] = __builtin_amdgcn_mfma_f32_16x16x32_bf16(af, bfr, acc[c], 0, 0, 0);
      }
    }
    __syncthreads();
  }
  int col = lane&15, rbase = m0 + wave*16 + (lane>>4)*4;
  #pragma unroll
  for (int c=0;c<4;c++){
    int n = n0 + c*16 + col;
    float bv = bias ? bias[n] : 0.f;
    #pragma unroll
    for (int i=0;i<4;i++) C[(size_t)(rbase+i)*N + n] = acc[c][i] + bv;
  }
}

// ---------------- pipelined MFMA core ----------------
// A,B tile-blocked swizzled: tile t of operand at base + t*MT_E, k-tile kt at +kt*TILE_E.
// MT/NT = 64-wide tiles of A/B; WAVES waves arranged WM x WN; wave tile = MF*16 x NF*16.
// Double-buffered, counted vmcnt (never 0 mid-loop), 2 barriers/k-tile.
template<int MT, int NT, int WAVES, int WM, int WN, int MF, int NF>
__device__ __forceinline__ void mmcore(const unsigned short* __restrict__ Ag,
                                       const unsigned short* __restrict__ Bg,
                                       unsigned short* sbuf,
                                       f32x4 (&acc)[MF][NF]){
  constexpr int TT = MT + NT;
  constexpr int L  = 8*TT/WAVES;          // global_load_lds per wave per k-tile
  static_assert(8*TT == L*WAVES, "load split");
  const int tid = threadIdx.x, wave = tid>>6, lane = tid&63;
  const int wm = wave / WN, wn = wave % WN;
  const int l8 = lane>>4, c15 = lane&15;

  // fragment LDS element offsets (within one buffer)
  int abase[MF], axr[MF];
  #pragma unroll
  for (int f=0; f<MF; f++){
    int row = wm*(MF*16) + f*16 + c15;
    abase[f] = ((row>>6)*TILE_E) + ((row&63)<<6);
    axr[f]   = row & 7;
  }
  int bbase[NF], bxr[NF];
  #pragma unroll
  for (int c=0; c<NF; c++){
    int cc = wn*(NF*16) + c*16 + c15;
    bbase[c] = ((MT + (cc>>6))*TILE_E) + ((cc&63)<<6);
    bxr[c]   = cc & 7;
  }

  // staging descriptors: wave handles contiguous loads j = wave*L .. +L-1
  const unsigned short* gsrc[L];
  unsigned short* ldst[L];
  #pragma unroll
  for (int i=0;i<L;i++){
    int j = wave*L + i;
    int tile = j>>3, sub = j&7;
    const unsigned short* base = (tile < MT) ? (Ag + (size_t)tile*MT_E)
                                             : (Bg + (size_t)(tile-MT)*MT_E);
    gsrc[i] = base + sub*512 + lane*8;
    ldst[i] = sbuf + tile*TILE_E + sub*512;   // wave-uniform; HW adds lane*16B
  }
  auto STG = [&](int kt, int b){
    #pragma unroll
    for (int i=0;i<L;i++)
      GLOAD16(gsrc[i] + (size_t)kt*TILE_E, ldst[i] + b*(TT*TILE_E));
  };

  STG(0,0);
  STG(1,1);
  waitv<L>();     // my kt=0 loads landed
  bar();          // everyone's kt=0 loads landed

  #pragma unroll
  for (int kt=0; kt<16; kt++){
    const int cb = kt & 1;
    const unsigned short* B0 = sbuf + cb*(TT*TILE_E);
    #pragma unroll
    for (int kk=0; kk<2; kk++){
      bf16x8 av[MF];
      #pragma unroll
      for (int f=0; f<MF; f++)
        av[f] = *(const bf16x8*)(B0 + abase[f] + (((kk*4 + l8) ^ axr[f])<<3));
      #pragma unroll
      for (int c=0; c<NF; c++){
        bf16x8 bv = *(const bf16x8*)(B0 + bbase[c] + (((kk*4 + l8) ^ bxr[c])<<3));
        #pragma unroll
        for (int f=0; f<MF; f++)
          acc[f][c] = __builtin_amdgcn_mfma_f32_16x16x32_bf16(av[f], bv, acc[f][c], 0,0,0);
      }
    }
    if (kt < 15){
      waitlgkm0();          // my ds_reads of buf cb complete
      bar();                // all waves done reading buf cb -> safe to overwrite
      if (kt < 14){
        STG(kt+2, cb);      // outstanding: kt+1 (L) + kt+2 (L)
        waitv<L>();         // kt+1's loads (issued one full phase ago) landed
      } else {
        waitv<0>();         // tail: only kt+1=15 in flight
      }
      bar();                // everyone's kt+1 loads landed
    }
  }
}

// ---------------- recurrence step ----------------
// defer grid (32,8): gates only (N=4096). fallback grid (38,8): gates + out tiles.
// block = 64 rows x 128 cols, 4 waves of 32x64 (NF=4 == one r/z/n/h gate quad).
__global__ __launch_bounds__(256) void gemm_rec(const unsigned short* __restrict__ hin,
    const float* __restrict__ hfin, const unsigned short* __restrict__ Wext,
    const float* __restrict__ cst, float* __restrict__ outp,
    unsigned short* __restrict__ hout, float* __restrict__ hfout){
  __shared__ __align__(16) unsigned short sbuf[2*3*TILE_E];
  int bx, by;
  if (gridDim.x == 32){
    // XCD swizzle: XCD q keeps bx in [4q,4q+4) across ALL steps -> its 1MB of
    // Wext panels stays L2-resident for the whole recurrence.
    int f = blockIdx.x + 32*blockIdx.y;
    int q = f & 7, mm = f >> 3;          // mm in [0,32)
    bx = q*4 + (mm>>3); by = mm & 7;
  } else { bx = blockIdx.x; by = blockIdx.y; }

  f32x4 acc[2][4] = {};
  mmcore<1,2,4,2,2,2,4>(hin + (size_t)by*MT_E, Wext + (size_t)(2*bx)*MT_E, sbuf, acc);

  const int tid = threadIdx.x, wave = tid>>6, lane = tid&63;
  const int wm = wave>>1, wn = wave&1, col = lane&15;
  const int rb = by*64 + wm*32 + ((lane>>4)<<2);
  if (bx < 32){
    const int g  = bx*2 + wn;            // gate quad (0..63)
    const int jj = g*16 + col;
    const int tb = (jj>>6)*TILE_E;
    #pragma unroll
    for (int f=0; f<2; f++){
      #pragma unroll
      for (int i=0;i<4;i++){
        int b = rb + f*16 + i;
        const float* cr = cst + (size_t)b*NEXT + g*64 + col;
        float r  = sigm(acc[f][0][i] + cr[0]);
        float z  = sigm(acc[f][1][i] + cr[16]);
        float nn = tanhf((acc[f][2][i] + cr[32]) + r*(acc[f][3][i] + cr[48]));
        float hn = nn + z*(hfin[(size_t)b*H + jj] - nn);
        hfout[(size_t)b*H + jj] = hn;
        hout[(size_t)(b>>6)*MT_E + tb + swz_off(b&63, jj&63)] = f2bf(hn);
      }
    }
  } else {
    const int o0 = (bx-32)*128 + wn*64;
    #pragma unroll
    for (int c=0;c<4;c++){
      int oc = o0 + c*16 + col;
      #pragma unroll
      for (int f=0; f<2; f++){
        #pragma unroll
        for (int i=0;i<4;i++){
          int b = rb + f*16 + i;
          outp[(size_t)b*OUTD + oc] = acc[f][c][i] + cst[(size_t)b*NEXT + 4096 + oc];
        }
      }
    }
  }
}

// ---------------- deferred output GEMM: out[s] = hist[s] @ fcW_h^T + fcctx ----------------
// grid (6,1024): 128x128 tiles, 8 waves of 32x64, 2 blocks/CU.
__global__ __launch_bounds__(512, 4) void gemm_out(const unsigned short* __restrict__ hist,
    const unsigned short* __restrict__ Wext, const float* __restrict__ fcctx,
    float* __restrict__ outp){
  __shared__ __align__(16) unsigned short sbuf[2*4*TILE_E];
  const int bx = blockIdx.x;     // out col tile (128-wide), 0..5
  const int gy = blockIdx.y;     // global 128-row tile, 0..1023
  f32x4 acc[2][4] = {};
  mmcore<2,2,8,4,2,2,4>(hist + (size_t)gy*2*MT_E, Wext + (size_t)(64 + 2*bx)*MT_E, sbuf, acc);
  const int tid = threadIdx.x, wave = tid>>6, lane = tid&63;
  const int wm = wave>>1, wn = wave&1, col = lane&15;
  #pragma unroll
  for (int f=0; f<2; f++){
    #pragma unroll
    for (int c=0; c<4; c++){
      int oc = bx*128 + wn*64 + c*16 + col;
      #pragma unroll
      for (int i=0;i<4;i++){
        int lr = wm*32 + f*16 + ((lane>>4)<<2) + i;
        size_t grow = (size_t)gy*128 + lr;
        size_t s = grow >> 9;            // slot (output step)
        int b = (int)(grow & 511);
        outp[(s*BSZ + b)*OUTD + oc] = acc[f][c][i] + fcctx[(size_t)b*OUTD + oc];
      }
    }
  }
}

// ---------------- host ----------------
extern "C" void kernel_launch(void* const* d_in, const int* in_sizes, int n_in,
                              void* d_out, int out_size, void* d_ws, size_t ws_size,
                              hipStream_t stream){
  const float* src    = (const float*)d_in[0];
  const float* hidden = (const float*)d_in[1];
  const float* W_ih   = (const float*)d_in[2];
  const float* W_hh   = (const float*)d_in[3];
  const float* b_ih   = (const float*)d_in[4];
  const float* b_hh   = (const float*)d_in[5];
  const float* fc_W   = (const float*)d_in[6];
  const float* fc_b   = (const float*)d_in[7];
  float* outp = (float*)d_out;

  char* p = (char*)d_ws;
  auto alloc = [&](size_t bytes){ char* r = p; p += (bytes + 255) & ~(size_t)255; return r; };
  unsigned short* Wih_bf   = (unsigned short*)alloc((size_t)N3H*OUTD*2);
  unsigned short* Whh_bf   = (unsigned short*)alloc((size_t)N3H*H*2);
  unsigned short* fcWbt    = (unsigned short*)alloc((size_t)OUTD*H*2);
  unsigned short* fcWT     = (unsigned short*)alloc((size_t)H*OUTD*2);
  unsigned short* ctx_bf   = (unsigned short*)alloc((size_t)BSZ*H*2);
  unsigned short* x0_bf    = (unsigned short*)alloc((size_t)BSZ*OUTD*2);
  float*          fcctx    = (float*)alloc((size_t)BSZ*OUTD*4);
  unsigned short* fcctx_bf = (unsigned short*)alloc((size_t)BSZ*OUTD*2);
  float*          Wcomb    = (float*)alloc((size_t)N3H*H*4);
  float*          dmat     = (float*)alloc((size_t)BSZ*N3H*4);
  unsigned short* Wext     = (unsigned short*)alloc((size_t)NEXT*H*2);
  float*          cst      = (float*)alloc((size_t)BSZ*NEXT*4);
  float*          gi       = (float*)alloc((size_t)BSZ*N3H*4);
  float*          gh       = (float*)alloc((size_t)BSZ*N3H*4);
  unsigned short* hbf      = (unsigned short*)alloc((size_t)2*BSZ*H*2);
  float*          hf       = (float*)alloc((size_t)2*BSZ*H*4);

  size_t used = (size_t)(p - (char*)d_ws);
  size_t hist_bytes = (size_t)TSTEPS*BSZ*H*2;   // 268 MB bf16 h-history
  bool defer = (used + hist_bytes + 4096) <= ws_size;
  unsigned short* hist = defer ? (unsigned short*)alloc(hist_bytes) : nullptr;

  auto cdiv = [](int a, int b){ return (a + b - 1)/b; };

  conv_bf<<<cdiv(N3H*OUTD,256),256,0,stream>>>(Wih_bf, W_ih, N3H*OUTD);
  conv_bf<<<cdiv(N3H*H,256),256,0,stream>>>(Whh_bf, W_hh, N3H*H);
  conv_bf<<<cdiv(BSZ*H,256),256,0,stream>>>(ctx_bf, hidden, BSZ*H);
  conv_bf<<<cdiv(BSZ*OUTD,256),256,0,stream>>>(x0_bf, src, BSZ*OUTD);
  conv_rows<<<cdiv(OUTD*H,256),256,0,stream>>>(fcWbt, fc_W, OUTD, H, 2*H, H);
  transp_fcw<<<dim3(16,12),256,0,stream>>>(fcWT, fc_W);

  gemm_bt<<<dim3(H/64, N3H/64),256,0,stream>>>(Wih_bf, fcWT, nullptr, Wcomb, H, OUTD);
  gemm_bt<<<dim3(OUTD/64, BSZ/64),256,0,stream>>>(ctx_bf, fcWbt, fc_b, fcctx, OUTD, H);
  conv_bf<<<cdiv(BSZ*OUTD,256),256,0,stream>>>(fcctx_bf, fcctx, BSZ*OUTD);
  gemm_bt<<<dim3(N3H/64, BSZ/64),256,0,stream>>>(fcctx_bf, Wih_bf, b_ih, dmat, N3H, OUTD);

  asm_wext<<<cdiv(NEXT*H,256),256,0,stream>>>(Wext, Wcomb, W_hh, fc_W);
  asm_const<<<cdiv(BSZ*NEXT,256),256,0,stream>>>(cst, dmat, fcctx, b_hh);

  gemm_bt<<<dim3(N3H/64, BSZ/64),256,0,stream>>>(x0_bf, Wih_bf, b_ih, gi, N3H, OUTD);
  gemm_bt<<<dim3(N3H/64, BSZ/64),256,0,stream>>>(ctx_bf, Whh_bf, b_hh, gh, N3H, H);

  if (defer){
    gru0<<<cdiv(BSZ*H,256),256,0,stream>>>(gi, gh, hidden, hist, hf + SLOT_E);
    for (int t=1; t<TSTEPS; t++){
      gemm_rec<<<dim3(32,8),256,0,stream>>>(
          hist + (size_t)(t-1)*SLOT_E, hf + (size_t)(t&1)*SLOT_E,
          Wext, cst, nullptr,
          hist + (size_t)t*SLOT_E, hf + (size_t)((t+1)&1)*SLOT_E);
    }
    gemm_out<<<dim3(6,1024),512,0,stream>>>(hist, Wext, fcctx, outp);
  } else {
    gru0<<<cdiv(BSZ*H,256),256,0,stream>>>(gi, gh, hidden, hbf + SLOT_E, hf + SLOT_E);
    for (int t=1; t<=TSTEPS; t++){
      gemm_rec<<<dim3(38,8),256,0,stream>>>(
          hbf + (size_t)(t&1)*SLOT_E, hf + (size_t)(t&1)*SLOT_E,
          Wext, cst, outp + (size_t)(t-1)*BSZ*OUTD,
          hbf + (size_t)((t+1)&1)*SLOT_E, hf + (size_t)((t+1)&1)*SLOT_E);
    }
  }
}